// Round 3
// baseline (318.496 us; speedup 1.0000x reference)
//
#include <hip/hip_runtime.h>

#define N_NODES 20000
#define DEG 6
#define E_EDGES 120000
#define D_IN 80
#define HID 128
#define OUT_D 128
#define EPS_BN 1e-5f

// ws float offsets (stats only; h3 lives in d_out)
#define WS_S0SUM 0
#define WS_S0SQ  80
#define WS_S1SUM 160
#define WS_S1SQ  288
#define WS_FSUM  416
#define WS_FSQ   544
#define WS_STATS_FLOATS 672

// ---------------------------------------------------------------- K1: bn0 stats
__global__ __launch_bounds__(256) void k1_bn0_stats(
    const float* __restrict__ node_attr, const float* __restrict__ edge_attr,
    float* __restrict__ ws) {
  __shared__ float red[256];
  const int t = threadIdx.x;
  const int b = blockIdx.x;
  if (b < 128) {  // node_attr: 20000 x 64 (per-node stats == per-edge stats, exact 6x repeat)
    const int c = t & 63, rl = t >> 6;
    float s = 0.f, q = 0.f;
    for (int row = b * 4 + rl; row < N_NODES; row += 512) {
      float v = node_attr[row * 64 + c];
      s += v; q += v * v;
    }
    red[t] = s;
    __syncthreads();
    if (t < 64) atomicAdd(&ws[WS_S0SUM + t], red[t] + red[t + 64] + red[t + 128] + red[t + 192]);
    __syncthreads();
    red[t] = q;
    __syncthreads();
    if (t < 64) atomicAdd(&ws[WS_S0SQ + t], red[t] + red[t + 64] + red[t + 128] + red[t + 192]);
  } else {  // edge_attr: 120000 x 16
    const int c = t & 15, rl = t >> 4;
    float s = 0.f, q = 0.f;
    for (int row = (b - 128) * 16 + rl; row < E_EDGES; row += 1024) {
      float v = edge_attr[row * 16 + c];
      s += v; q += v * v;
    }
    red[t] = s;
    __syncthreads();
    if (t < 16) {
      float tot = 0.f;
      #pragma unroll
      for (int k = 0; k < 16; ++k) tot += red[t + 16 * k];
      atomicAdd(&ws[WS_S0SUM + 64 + t], tot);
    }
    __syncthreads();
    red[t] = q;
    __syncthreads();
    if (t < 16) {
      float tot = 0.f;
      #pragma unroll
      for (int k = 0; k < 16; ++k) tot += red[t + 16 * k];
      atomicAdd(&ws[WS_S0SQ + 64 + t], tot);
    }
  }
}

// ------------------------------------------- K2: GEMM1 pass -> bn1 column stats
__global__ __launch_bounds__(256) void k2_gemm1_stats(
    const float* __restrict__ node_attr, const float* __restrict__ edge_attr,
    const float* __restrict__ bn0_g, const float* __restrict__ bn0_b,
    const float* __restrict__ W1, float* __restrict__ ws) {
  __shared__ float W1s[80][128];
  __shared__ float h0s[64][80];
  __shared__ float sc0[80], sh0[80];
  __shared__ float red[8][128];
  const int t = threadIdx.x;
  if (t < 80) {
    float cnt = (t < 64) ? (float)N_NODES : (float)E_EDGES;
    float mu = ws[WS_S0SUM + t] / cnt;
    float var = ws[WS_S0SQ + t] / cnt - mu * mu;
    float sc = bn0_g[t] * rsqrtf(var + EPS_BN);
    sc0[t] = sc;
    sh0[t] = bn0_b[t] - mu * sc;
  }
  for (int i = t; i < 80 * 128 / 4; i += 256)
    ((float4*)W1s)[i] = ((const float4*)W1)[i];
  __syncthreads();

  const int tx = t & 31, ty = t >> 5;
  const int c0 = tx * 4, r0 = ty * 8;
  float csum[4] = {0.f, 0.f, 0.f, 0.f}, csq[4] = {0.f, 0.f, 0.f, 0.f};

  for (int tile = blockIdx.x; tile < E_EDGES / 64; tile += gridDim.x) {
    __syncthreads();  // protect h0s reuse
    const int ebase = tile * 64;
    for (int i = t; i < 64 * 80; i += 256) {
      int r = i / 80, c = i % 80;
      int ge = ebase + r;
      float v = (c < 64) ? node_attr[(ge / DEG) * 64 + c] : edge_attr[ge * 16 + (c - 64)];
      h0s[r][c] = v * sc0[c] + sh0[c];
    }
    __syncthreads();
    float acc[8][4];
    #pragma unroll
    for (int i = 0; i < 8; ++i)
      #pragma unroll
      for (int j = 0; j < 4; ++j) acc[i][j] = 0.f;
    #pragma unroll 4
    for (int k = 0; k < 80; ++k) {
      float4 b4 = *(const float4*)&W1s[k][c0];
      #pragma unroll
      for (int i = 0; i < 8; ++i) {
        float a = h0s[r0 + i][k];
        acc[i][0] += a * b4.x; acc[i][1] += a * b4.y;
        acc[i][2] += a * b4.z; acc[i][3] += a * b4.w;
      }
    }
    #pragma unroll
    for (int i = 0; i < 8; ++i)
      #pragma unroll
      for (int j = 0; j < 4; ++j) {
        float v = acc[i][j];
        csum[j] += v; csq[j] += v * v;
      }
  }
  __syncthreads();
  #pragma unroll
  for (int j = 0; j < 4; ++j) red[ty][c0 + j] = csum[j];
  __syncthreads();
  if (t < 128) {
    float s = 0.f;
    #pragma unroll
    for (int k = 0; k < 8; ++k) s += red[k][t];
    atomicAdd(&ws[WS_S1SUM + t], s);
  }
  __syncthreads();
  #pragma unroll
  for (int j = 0; j < 4; ++j) red[ty][c0 + j] = csq[j];
  __syncthreads();
  if (t < 128) {
    float s = 0.f;
    #pragma unroll
    for (int k = 0; k < 8; ++k) s += red[k][t];
    atomicAdd(&ws[WS_S1SQ + t], s);
  }
}

// ---- K3: fused GEMM1(recompute)+bn1+relu -> GEMM2 -> 6x6 attention -> pool ----
__global__ __launch_bounds__(512) void k3_fused(
    const float* __restrict__ node_attr, const float* __restrict__ edge_attr,
    const float* __restrict__ bn0_g, const float* __restrict__ bn0_b,
    const float* __restrict__ W1,
    const float* __restrict__ bn1_g, const float* __restrict__ bn1_b,
    const float* __restrict__ Wg,
    const float* __restrict__ att_src, const float* __restrict__ att_dst,
    const float* __restrict__ gat_bias,
    float* __restrict__ out, float* __restrict__ ws) {
  __shared__ float W1s[80][128];    // 40 KB
  __shared__ float Wgs[128][128];   // 64 KB
  __shared__ float h0s[48][80];     // 15 KB
  __shared__ float h1s[48][128];    // 24 KB
  __shared__ float sc0[80], sh0[80], sc1[128], sh1[128];
  __shared__ float asL[48], adL[48], alphaL[48][6], wL[48];
  __shared__ float red[8][128];     // 4 KB

  const int t = threadIdx.x;
  if (t < 80) {
    float cnt = (t < 64) ? (float)N_NODES : (float)E_EDGES;
    float mu = ws[WS_S0SUM + t] / cnt;
    float var = ws[WS_S0SQ + t] / cnt - mu * mu;
    float sc = bn0_g[t] * rsqrtf(var + EPS_BN);
    sc0[t] = sc; sh0[t] = bn0_b[t] - mu * sc;
  }
  if (t < 128) {
    const float invE = 1.f / (float)E_EDGES;
    float mu = ws[WS_S1SUM + t] * invE;
    float var = ws[WS_S1SQ + t] * invE - mu * mu;
    float sc = bn1_g[t] * rsqrtf(var + EPS_BN);
    sc1[t] = sc; sh1[t] = bn1_b[t] - mu * sc;
  }
  for (int i = t; i < 80 * 128 / 4; i += 512)
    ((float4*)W1s)[i] = ((const float4*)W1)[i];
  for (int i = t; i < 128 * 128 / 4; i += 512)
    ((float4*)Wgs)[i] = ((const float4*)Wg)[i];

  const int tx = t & 31, ty = t >> 5;     // ty 0..15
  const int c0 = tx * 4, r0 = ty * 3;     // 48 rows, 128 cols
  const float4 attS4 = *(const float4*)&att_src[c0];
  const float4 attD4 = *(const float4*)&att_dst[c0];
  const float4 gb4 = *(const float4*)&gat_bias[c0];
  float fs[4] = {0.f, 0.f, 0.f, 0.f}, fq[4] = {0.f, 0.f, 0.f, 0.f};

  for (int g = blockIdx.x; g < N_NODES / 8; g += gridDim.x) {
    __syncthreads();  // protect LDS reuse from previous iteration
    const int ebase = g * 48;
    for (int i = t; i < 48 * 80; i += 512) {
      int r = i / 80, c = i % 80;
      int ge = ebase + r;
      float v = (c < 64) ? node_attr[(ge / DEG) * 64 + c] : edge_attr[ge * 16 + (c - 64)];
      h0s[r][c] = v * sc0[c] + sh0[c];
    }
    __syncthreads();
    // GEMM1: h1 = relu(bn1(h0bn @ W1))
    {
      float acc[3][4];
      #pragma unroll
      for (int i = 0; i < 3; ++i)
        #pragma unroll
        for (int j = 0; j < 4; ++j) acc[i][j] = 0.f;
      #pragma unroll 4
      for (int k = 0; k < 80; ++k) {
        float4 b4 = *(const float4*)&W1s[k][c0];
        #pragma unroll
        for (int i = 0; i < 3; ++i) {
          float a = h0s[r0 + i][k];
          acc[i][0] += a * b4.x; acc[i][1] += a * b4.y;
          acc[i][2] += a * b4.z; acc[i][3] += a * b4.w;
        }
      }
      #pragma unroll
      for (int i = 0; i < 3; ++i) {
        float4 o;
        o.x = fmaxf(acc[i][0] * sc1[c0 + 0] + sh1[c0 + 0], 0.f);
        o.y = fmaxf(acc[i][1] * sc1[c0 + 1] + sh1[c0 + 1], 0.f);
        o.z = fmaxf(acc[i][2] * sc1[c0 + 2] + sh1[c0 + 2], 0.f);
        o.w = fmaxf(acc[i][3] * sc1[c0 + 3] + sh1[c0 + 3], 0.f);
        *(float4*)&h1s[r0 + i][c0] = o;
      }
    }
    __syncthreads();
    // GEMM2: x = h1 @ Wg (kept in registers)
    float acc2[3][4];
    #pragma unroll
    for (int i = 0; i < 3; ++i)
      #pragma unroll
      for (int j = 0; j < 4; ++j) acc2[i][j] = 0.f;
    #pragma unroll 4
    for (int k = 0; k < 128; ++k) {
      float4 b4 = *(const float4*)&Wgs[k][c0];
      #pragma unroll
      for (int i = 0; i < 3; ++i) {
        float a = h1s[r0 + i][k];
        acc2[i][0] += a * b4.x; acc2[i][1] += a * b4.y;
        acc2[i][2] += a * b4.z; acc2[i][3] += a * b4.w;
      }
    }
    // a_src / a_dst row reductions (over 32 tx lanes within each half-wave)
    float ps[3], pd[3];
    #pragma unroll
    for (int i = 0; i < 3; ++i) {
      ps[i] = acc2[i][0] * attS4.x + acc2[i][1] * attS4.y + acc2[i][2] * attS4.z + acc2[i][3] * attS4.w;
      pd[i] = acc2[i][0] * attD4.x + acc2[i][1] * attD4.y + acc2[i][2] * attD4.z + acc2[i][3] * attD4.w;
    }
    #pragma unroll
    for (int off = 1; off < 32; off <<= 1) {
      #pragma unroll
      for (int i = 0; i < 3; ++i) {
        ps[i] += __shfl_xor(ps[i], off);
        pd[i] += __shfl_xor(pd[i], off);
      }
    }
    if (tx == 0) {
      #pragma unroll
      for (int i = 0; i < 3; ++i) { asL[r0 + i] = ps[i]; adL[r0 + i] = pd[i]; }
    }
    __syncthreads();
    // attention: per (node n, dest j) softmax over the 6 group members
    if (t < 48) {
      int n = t / 6, j = t % 6, nb = n * 6;
      float ad = adL[nb + j];
      float s6[6]; float m = -1e30f;
      #pragma unroll
      for (int i = 0; i < 6; ++i) {
        float s = asL[nb + i] + ad;
        s = (s > 0.f) ? s : 0.2f * s;
        s6[i] = s; m = fmaxf(m, s);
      }
      float ssum = 0.f; float ex[6];
      #pragma unroll
      for (int i = 0; i < 6; ++i) { ex[i] = __expf(s6[i] - m); ssum += ex[i]; }
      float inv = 1.f / (ssum + 1e-16f);
      #pragma unroll
      for (int i = 0; i < 6; ++i) alphaL[nb + j][i] = ex[i] * inv;
    }
    __syncthreads();
    if (t < 48) {  // w_i = sum_j alpha_ij
      int n = t / 6, i = t % 6;
      float w = 0.f;
      #pragma unroll
      for (int j = 0; j < 6; ++j) w += alphaL[n * 6 + j][i];
      wL[t] = w;
    }
    __syncthreads();
    // h3[n][c] = sum_i w_i * x_i[c] + 6*gat_bias[c]
    float p[4] = {0.f, 0.f, 0.f, 0.f};
    #pragma unroll
    for (int i = 0; i < 3; ++i) {
      float w = wL[r0 + i];
      p[0] += w * acc2[i][0]; p[1] += w * acc2[i][1];
      p[2] += w * acc2[i][2]; p[3] += w * acc2[i][3];
    }
    #pragma unroll
    for (int j = 0; j < 4; ++j) p[j] += __shfl_xor(p[j], 32);  // combine row-halves of node
    if ((ty & 1) == 0) {
      int node = g * 8 + (ty >> 1);
      float4 o;
      o.x = p[0] + 6.f * gb4.x; o.y = p[1] + 6.f * gb4.y;
      o.z = p[2] + 6.f * gb4.z; o.w = p[3] + 6.f * gb4.w;
      *(float4*)&out[node * OUT_D + c0] = o;
      fs[0] += o.x; fq[0] += o.x * o.x;
      fs[1] += o.y; fq[1] += o.y * o.y;
      fs[2] += o.z; fq[2] += o.z * o.z;
      fs[3] += o.w; fq[3] += o.w * o.w;
    }
  }
  // bnf column stats
  __syncthreads();
  if ((ty & 1) == 0) {
    #pragma unroll
    for (int j = 0; j < 4; ++j) red[ty >> 1][c0 + j] = fs[j];
  }
  __syncthreads();
  if (t < 128) {
    float s = 0.f;
    #pragma unroll
    for (int k = 0; k < 8; ++k) s += red[k][t];
    atomicAdd(&ws[WS_FSUM + t], s);
  }
  __syncthreads();
  if ((ty & 1) == 0) {
    #pragma unroll
    for (int j = 0; j < 4; ++j) red[ty >> 1][c0 + j] = fq[j];
  }
  __syncthreads();
  if (t < 128) {
    float s = 0.f;
    #pragma unroll
    for (int k = 0; k < 8; ++k) s += red[k][t];
    atomicAdd(&ws[WS_FSQ + t], s);
  }
}

// ------------------------------------------ K4: final BN applied in-place on out
__global__ __launch_bounds__(256) void k4_final(
    float* __restrict__ out, const float* __restrict__ ws,
    const float* __restrict__ bnf_g, const float* __restrict__ bnf_b) {
  int idx4 = blockIdx.x * 256 + threadIdx.x;
  if (idx4 >= N_NODES * OUT_D / 4) return;
  int c0 = (idx4 & 31) << 2;
  float4 v = ((float4*)out)[idx4];
  float4 fs = *(const float4*)&ws[WS_FSUM + c0];
  float4 fq = *(const float4*)&ws[WS_FSQ + c0];
  float4 g4 = *(const float4*)&bnf_g[c0];
  float4 b4 = *(const float4*)&bnf_b[c0];
  const float invN = 1.f / (float)N_NODES;
  float mu, var, sc;
  mu = fs.x * invN; var = fq.x * invN - mu * mu; sc = g4.x * rsqrtf(var + EPS_BN);
  v.x = (v.x - mu) * sc + b4.x;
  mu = fs.y * invN; var = fq.y * invN - mu * mu; sc = g4.y * rsqrtf(var + EPS_BN);
  v.y = (v.y - mu) * sc + b4.y;
  mu = fs.z * invN; var = fq.z * invN - mu * mu; sc = g4.z * rsqrtf(var + EPS_BN);
  v.z = (v.z - mu) * sc + b4.z;
  mu = fs.w * invN; var = fq.w * invN - mu * mu; sc = g4.w * rsqrtf(var + EPS_BN);
  v.w = (v.w - mu) * sc + b4.w;
  ((float4*)out)[idx4] = v;
}

extern "C" void kernel_launch(void* const* d_in, const int* in_sizes, int n_in,
                              void* d_out, int out_size, void* d_ws, size_t ws_size,
                              hipStream_t stream) {
  const float* edge_attr = (const float*)d_in[0];
  const float* node_attr = (const float*)d_in[1];
  const float* bn0_g = (const float*)d_in[2];
  const float* bn0_b = (const float*)d_in[3];
  const float* W1    = (const float*)d_in[4];
  const float* bn1_g = (const float*)d_in[5];
  const float* bn1_b = (const float*)d_in[6];
  const float* Wg    = (const float*)d_in[7];
  const float* att_src = (const float*)d_in[8];
  const float* att_dst = (const float*)d_in[9];
  const float* gat_bias = (const float*)d_in[10];
  const float* bnf_g = (const float*)d_in[11];
  const float* bnf_b = (const float*)d_in[12];
  float* ws = (float*)d_ws;
  float* out = (float*)d_out;

  hipMemsetAsync(d_ws, 0, WS_STATS_FLOATS * sizeof(float), stream);
  k1_bn0_stats<<<192, 256, 0, stream>>>(node_attr, edge_attr, ws);
  k2_gemm1_stats<<<512, 256, 0, stream>>>(node_attr, edge_attr, bn0_g, bn0_b, W1, ws);
  k3_fused<<<250, 512, 0, stream>>>(node_attr, edge_attr, bn0_g, bn0_b, W1,
                                    bn1_g, bn1_b, Wg, att_src, att_dst, gat_bias,
                                    out, ws);
  k4_final<<<2500, 256, 0, stream>>>(out, ws, bnf_g, bnf_b);
}